// Round 8
// baseline (252.390 us; speedup 1.0000x reference)
//
#include <hip/hip_runtime.h>

#define NROWS 262144
#define NCOLS 128
#define TPB 256
#define WPB (TPB / 64)
#define NBLOCKS 4096
#define NWAVES (NBLOCKS * WPB)    // 16384 waves
#define NPAIRS (NROWS / 2)        // 131072
#define U 8                       // pairs per wave, single pass: 16384*8 = 131072

typedef float floatx4 __attribute__((ext_vector_type(4)));

__device__ __forceinline__ floatx4 ntload4(const float* p)
{
    return __builtin_nontemporal_load((const floatx4*)p);
}

// Lanes 0-31 -> row 2p, lanes 32-63 -> row 2p+1; each lane loads one float4
// of x and t per pair (wave covers 1KB contiguous per array per pair).
// Single pass: each wave owns 8 consecutive pairs, issues all 16 nt loads
// back-to-back, then sched_barrier(0) pins the load block above processing
// so all 16 KB/wave stay in flight. nt policy avoids L2/L3 allocation and
// the dirty-victim writebacks of the harness's restore data (R7 win).
__global__ __launch_bounds__(TPB, 4) void biased_loss_partial(
    const float* __restrict__ x, const float* __restrict__ t,
    float* __restrict__ partial)
{
    const int lane = threadIdx.x & 63;
    const int waveInBlock = threadIdx.x >> 6;
    const int gw = blockIdx.x * WPB + waveInBlock;
    const int half = lane >> 5;
    const int sub  = lane & 31;

    const int pbase = gw * U;

    floatx4 xv[U], tv[U];
    #pragma unroll
    for (int u = 0; u < U; ++u) {
        const size_t base =
            (size_t)(2 * (pbase + u) + half) * NCOLS + (size_t)sub * 4;
        xv[u] = ntload4(x + base);
        tv[u] = ntload4(t + base);
    }
    __builtin_amdgcn_sched_barrier(0);   // keep all 16 loads issued first

    float acc = 0.0f;
    #pragma unroll
    for (int u = 0; u < U; ++u) {
        const int c = sub * 4;
        float bv = xv[u].x; int bi = c;
        if (xv[u].y > bv) { bv = xv[u].y; bi = c + 1; }
        if (xv[u].z > bv) { bv = xv[u].z; bi = c + 2; }
        if (xv[u].w > bv) { bv = xv[u].w; bi = c + 3; }

        // butterfly argmax across the 32-lane half (off<=16 stays in half)
        #pragma unroll
        for (int off = 16; off > 0; off >>= 1) {
            float ov = __shfl_xor(bv, off, 64);
            int   oi = __shfl_xor(bi, off, 64);
            if (ov > bv || (ov == bv && oi < bi)) { bv = ov; bi = oi; }
        }

        float t0 = __shfl(tv[u].x, half << 5, 64);
        const bool cond = (bi > 0) && (t0 == 0.0f);

        float c0 = fabsf(xv[u].x * tv[u].x);
        float c1 = fabsf(xv[u].y * tv[u].y);
        float c2 = fabsf(xv[u].z * tv[u].z);
        float c3 = fabsf(xv[u].w * tv[u].w);

        float s;
        if (cond) {
            s = (c     == bi ? c0 : 0.0f)
              + (c + 1 == bi ? c1 : 0.0f)
              + (c + 2 == bi ? c2 : 0.0f)
              + (c + 3 == bi ? c3 : 0.0f);
        } else {
            s = (c0 + c1) + (c2 + c3);
        }
        acc += s;
    }

    // full-wave sum
    #pragma unroll
    for (int off = 32; off > 0; off >>= 1)
        acc += __shfl_xor(acc, off, 64);

    __shared__ float smem[WPB];
    if (lane == 0) smem[waveInBlock] = acc;
    __syncthreads();
    if (threadIdx.x == 0) {
        float bsum = 0.0f;
        #pragma unroll
        for (int w = 0; w < WPB; ++w) bsum += smem[w];
        partial[blockIdx.x] = bsum;
    }
}

__global__ __launch_bounds__(256) void reduce_partials(
    const float* __restrict__ partial, float* __restrict__ out, int n)
{
    float acc = 0.0f;
    for (int i = threadIdx.x; i < n; i += 256) acc += partial[i];
    #pragma unroll
    for (int off = 32; off > 0; off >>= 1)
        acc += __shfl_xor(acc, off, 64);
    __shared__ float smem[4];
    const int lane = threadIdx.x & 63, w = threadIdx.x >> 6;
    if (lane == 0) smem[w] = acc;
    __syncthreads();
    if (threadIdx.x == 0) {
        float s = smem[0] + smem[1] + smem[2] + smem[3];
        out[0] = s / (float)((size_t)NROWS * (size_t)NCOLS);
    }
}

extern "C" void kernel_launch(void* const* d_in, const int* in_sizes, int n_in,
                              void* d_out, int out_size, void* d_ws, size_t ws_size,
                              hipStream_t stream) {
    const float* x = (const float*)d_in[0];
    const float* t = (const float*)d_in[1];
    float* partial = (float*)d_ws;  // NBLOCKS * 4 B = 16 KiB scratch

    biased_loss_partial<<<NBLOCKS, TPB, 0, stream>>>(x, t, partial);
    reduce_partials<<<1, 256, 0, stream>>>(partial, (float*)d_out, NBLOCKS);
}